// Round 2
// baseline (373.076 us; speedup 1.0000x reference)
//
#include <hip/hip_runtime.h>
#include <hip/hip_bf16.h>
#include <stdint.h>

// QKV projection: C[M,N] = A[M,K] * W[N,K]^T + bias[N]
// M=16384, N=3072, K=1024. Reference dtypes are fp32; graded at bf16
// tolerance -> convert A/W to bf16 in d_ws, run m97-structure bf16 GEMM
// (128x128 tile, BK=32, global_load_lds width=16, 16x16x32 bf16 MFMA),
// accumulate fp32, store per detected output dtype.
//
// Runtime dtype probe (flag in d_ws): fp32 data read as bf16 pairs has
// uniformly-random exponents in the low halves; bf16 N(0,1) data never
// has exponent > 0x90. Branches on the flag are wave-uniform.

typedef __attribute__((ext_vector_type(8))) short short8;   // 8 x bf16
typedef __attribute__((ext_vector_type(4))) float f32x4;    // MFMA acc

#define BM 128
#define BN 128
#define BK 32
#define MTOT 16384
#define NTOT 3072
#define KTOT 1024

// ws layout (bytes)
#define WS_A_OFF    0u
#define WS_A_BYTES  (MTOT * KTOT * 2u)              // 33554432
#define WS_W_OFF    (WS_A_OFF + WS_A_BYTES)
#define WS_W_BYTES  (NTOT * KTOT * 2u)              // 6291456
#define WS_BIAS_OFF (WS_W_OFF + WS_W_BYTES)         // 39845888
#define WS_BIAS_BYTES (NTOT * 4u)
#define WS_FLAG_OFF (WS_BIAS_OFF + WS_BIAS_BYTES)   // 39858176

__global__ void detect_dtype(const unsigned* __restrict__ q, unsigned* __restrict__ flag) {
    __shared__ int s;
    const int t = threadIdx.x;
    if (t == 0) s = 0;
    __syncthreads();
    int cnt = 0;
    for (int i = t; i < 1024; i += 256) {
        unsigned e = (q[i] >> 7) & 0xFFu;   // exponent of low 16 bits as bf16
        cnt += (e > 0x90u) ? 1 : 0;
    }
    atomicAdd(&s, cnt);
    __syncthreads();
    if (t == 0) *flag = (s > 32) ? 1u : 0u;   // 1 = fp32 buffers, 0 = bf16
}

// n elements, n % 8 == 0. fp32->bf16 (RNE) or bf16 passthrough copy.
__global__ void cvt_to_bf16(const void* __restrict__ src, __hip_bfloat16* __restrict__ dst,
                            int n, const unsigned* __restrict__ flag) {
    const long i = (long)(blockIdx.x * 256 + threadIdx.x) * 8;
    if (i >= n) return;
    if (*flag) {
        const float* s = (const float*)src + i;
        __hip_bfloat16 tmp[8];
        #pragma unroll
        for (int k = 0; k < 8; ++k) tmp[k] = __float2bfloat16(s[k]);
        *(short8*)((short*)dst + i) = *(const short8*)tmp;
    } else {
        *(short8*)((short*)dst + i) = *(const short8*)((const short*)src + i);
    }
}

__global__ void cvt_bias(const void* __restrict__ src, float* __restrict__ dst,
                         const unsigned* __restrict__ flag) {
    const int i = blockIdx.x * 256 + threadIdx.x;
    if (i >= NTOT) return;
    dst[i] = *flag ? ((const float*)src)[i]
                   : __bfloat162float(((const __hip_bfloat16*)src)[i]);
}

__device__ __forceinline__ void gload_lds16(const void* g, void* l) {
    __builtin_amdgcn_global_load_lds(
        (const __attribute__((address_space(1))) void*)g,
        (__attribute__((address_space(3))) void*)l,
        16, 0, 0);
}

__global__ __launch_bounds__(256) void qkv_gemm_bt(
    const __hip_bfloat16* __restrict__ A,     // [M,K] bf16 (ws)
    const __hip_bfloat16* __restrict__ W,     // [N,K] bf16 (ws)
    const float* __restrict__ bias,           // [N] f32 (ws)
    void* __restrict__ Craw,                  // [M,N] f32 or bf16 per flag
    const unsigned* __restrict__ flag)
{
    __shared__ __align__(16) __hip_bfloat16 lds_a[BM * BK];
    __shared__ __align__(16) __hip_bfloat16 lds_b[BN * BK];

    const int t    = threadIdx.x;
    const int lane = t & 63;
    const int wave = t >> 6;

    const int m0 = blockIdx.y * BM;
    const int n0 = blockIdx.x * BN;

    // staging: thread t covers tile elements [t*8 .. t*8+7]; row=t>>2, col=(t&3)*8
    const int srow = t >> 2;
    const int scol = (t & 3) * 8;
    const __hip_bfloat16* gA0 = A + (size_t)(m0 + srow) * KTOT + scol;
    const __hip_bfloat16* gA1 = gA0 + (size_t)64 * KTOT;
    const __hip_bfloat16* gB0 = W + (size_t)(n0 + srow) * KTOT + scol;
    const __hip_bfloat16* gB1 = gB0 + (size_t)64 * KTOT;

    char* lA = (char*)lds_a + wave * 1024;    // wave-uniform base; HW adds lane*16
    char* lB = (char*)lds_b + wave * 1024;

    const int wrow = (wave >> 1) * 64;
    const int wcol = (wave & 1) * 64;
    const int fr   = lane & 15;
    const int quad = lane >> 4;

    const unsigned isf32 = *flag;             // uniform

    f32x4 acc[4][4];
    #pragma unroll
    for (int i = 0; i < 4; ++i)
        #pragma unroll
        for (int j = 0; j < 4; ++j)
            acc[i][j] = (f32x4){0.f, 0.f, 0.f, 0.f};

    const short* sa = (const short*)lds_a;
    const short* sb = (const short*)lds_b;

    for (int kt = 0; kt < KTOT / BK; ++kt) {
        if (kt) __syncthreads();
        const int kb = kt * BK;
        gload_lds16(gA0 + kb, lA);
        gload_lds16(gA1 + kb, lA + 4096);
        gload_lds16(gB0 + kb, lB);
        gload_lds16(gB1 + kb, lB + 4096);
        __syncthreads();                      // drains vmcnt before barrier

        short8 af[4], bf[4];
        #pragma unroll
        for (int i = 0; i < 4; ++i)
            af[i] = *(const short8*)(sa + (wrow + i * 16 + fr) * BK + quad * 8);
        #pragma unroll
        for (int j = 0; j < 4; ++j)
            bf[j] = *(const short8*)(sb + (wcol + j * 16 + fr) * BK + quad * 8);

        #pragma unroll
        for (int i = 0; i < 4; ++i)
            #pragma unroll
            for (int j = 0; j < 4; ++j)
                acc[i][j] = __builtin_amdgcn_mfma_f32_16x16x32_bf16(
                    af[i], bf[j], acc[i][j], 0, 0, 0);
    }

    // epilogue: C/D layout col=lane&15, row=quad*4+reg (m89-verified)
    float bv[4];
    #pragma unroll
    for (int j = 0; j < 4; ++j)
        bv[j] = bias[n0 + wcol + j * 16 + fr];

    if (isf32) {
        float* C = (float*)Craw;
        #pragma unroll
        for (int i = 0; i < 4; ++i) {
            const int row = m0 + wrow + i * 16 + quad * 4;
            #pragma unroll
            for (int j = 0; j < 4; ++j) {
                float* p = C + (size_t)row * NTOT + (n0 + wcol + j * 16 + fr);
                #pragma unroll
                for (int r = 0; r < 4; ++r)
                    p[(size_t)r * NTOT] = acc[i][j][r] + bv[j];
            }
        }
    } else {
        __hip_bfloat16* C = (__hip_bfloat16*)Craw;
        #pragma unroll
        for (int i = 0; i < 4; ++i) {
            const int row = m0 + wrow + i * 16 + quad * 4;
            #pragma unroll
            for (int j = 0; j < 4; ++j) {
                __hip_bfloat16* p = C + (size_t)row * NTOT + (n0 + wcol + j * 16 + fr);
                #pragma unroll
                for (int r = 0; r < 4; ++r)
                    p[(size_t)r * NTOT] = __float2bfloat16(acc[i][j][r] + bv[j]);
            }
        }
    }
}

extern "C" void kernel_launch(void* const* d_in, const int* in_sizes, int n_in,
                              void* d_out, int out_size, void* d_ws, size_t ws_size,
                              hipStream_t stream) {
    char* ws = (char*)d_ws;
    __hip_bfloat16* wsA    = (__hip_bfloat16*)(ws + WS_A_OFF);
    __hip_bfloat16* wsW    = (__hip_bfloat16*)(ws + WS_W_OFF);
    float*          wsBias = (float*)(ws + WS_BIAS_OFF);
    unsigned*       wsFlag = (unsigned*)(ws + WS_FLAG_OFF);

    detect_dtype<<<1, 256, 0, stream>>>((const unsigned*)d_in[0], wsFlag);

    const int nA = MTOT * KTOT;   // 16777216
    const int nW = NTOT * KTOT;   // 3145728
    cvt_to_bf16<<<nA / (256 * 8), 256, 0, stream>>>(d_in[0], wsA, nA, wsFlag);
    cvt_to_bf16<<<nW / (256 * 8), 256, 0, stream>>>(d_in[1], wsW, nW, wsFlag);
    cvt_bias<<<(NTOT + 255) / 256, 256, 0, stream>>>(d_in[2], wsBias, wsFlag);

    dim3 grid(NTOT / BN, MTOT / BM);   // (24, 128)
    qkv_gemm_bt<<<grid, 256, 0, stream>>>(wsA, wsW, wsBias, d_out, wsFlag);
}

// Round 3
// 362.391 us; speedup vs baseline: 1.0295x; 1.0295x over previous
//
#include <hip/hip_runtime.h>
#include <hip/hip_bf16.h>
#include <stdint.h>

// QKV projection: C[M,N] = A[M,K] * W[N,K]^T + bias[N]
// M=16384, N=3072, K=1024. Input/output dtypes HW-confirmed fp32 (R2:
// passed via fp32 path; WRITE_SIZE == M*N*4). Graded at bf16 tolerance ->
// convert A/W fp32->bf16 into d_ws (one fused vectorized pass), then run
// the verified m97-structure bf16 GEMM (128x128 tile, BK=32,
// global_load_lds width=16, 16x16x32 bf16 MFMA), fp32 accumulate,
// fp32 bias read directly from d_in[2], fp32 store.

typedef __attribute__((ext_vector_type(8))) short short8;            // 8 x bf16
typedef __attribute__((ext_vector_type(8))) unsigned short ushort8;  // 8 x bf16 bits
typedef __attribute__((ext_vector_type(4))) float f32x4;             // MFMA acc / float4

#define BM 128
#define BN 128
#define BK 32
#define MTOT 16384
#define NTOT 3072
#define KTOT 1024

// ws layout (bytes): A bf16 [M*K], then W bf16 [N*K]
#define WS_A_OFF   0u
#define WS_A_BYTES (MTOT * KTOT * 2u)   // 33554432
#define WS_W_OFF   (WS_A_OFF + WS_A_BYTES)

// ---- fused fp32->bf16 convert for A and W -------------------------------
// A: 16777216 elems = 8192 blocks * 2048; W: 3145728 = 1536 blocks * 2048.
// Branch on blockIdx is block-uniform. All data stays in VGPRs.
__global__ __launch_bounds__(256) void cvt_aw(
    const float* __restrict__ A, const float* __restrict__ W,
    unsigned short* __restrict__ dA, unsigned short* __restrict__ dW)
{
    const float* src;
    unsigned short* dst;
    long i;
    if (blockIdx.x < 8192) {
        src = A; dst = dA;
        i = ((long)blockIdx.x * 256 + threadIdx.x) * 8;
    } else {
        src = W; dst = dW;
        i = ((long)(blockIdx.x - 8192) * 256 + threadIdx.x) * 8;
    }
    f32x4 a = *(const f32x4*)(src + i);
    f32x4 b = *(const f32x4*)(src + i + 4);
    ushort8 r;
    r[0] = __bfloat16_as_ushort(__float2bfloat16(a[0]));
    r[1] = __bfloat16_as_ushort(__float2bfloat16(a[1]));
    r[2] = __bfloat16_as_ushort(__float2bfloat16(a[2]));
    r[3] = __bfloat16_as_ushort(__float2bfloat16(a[3]));
    r[4] = __bfloat16_as_ushort(__float2bfloat16(b[0]));
    r[5] = __bfloat16_as_ushort(__float2bfloat16(b[1]));
    r[6] = __bfloat16_as_ushort(__float2bfloat16(b[2]));
    r[7] = __bfloat16_as_ushort(__float2bfloat16(b[3]));
    *(ushort8*)(dst + i) = r;
}

__device__ __forceinline__ void gload_lds16(const void* g, void* l) {
    __builtin_amdgcn_global_load_lds(
        (const __attribute__((address_space(1))) void*)g,
        (__attribute__((address_space(3))) void*)l,
        16, 0, 0);
}

__global__ __launch_bounds__(256) void qkv_gemm_bt(
    const __hip_bfloat16* __restrict__ A,     // [M,K] bf16 (ws)
    const __hip_bfloat16* __restrict__ W,     // [N,K] bf16 (ws)
    const float* __restrict__ bias,           // [N] f32 (d_in[2])
    float* __restrict__ C)                    // [M,N] f32 (d_out)
{
    __shared__ __align__(16) __hip_bfloat16 lds_a[BM * BK];
    __shared__ __align__(16) __hip_bfloat16 lds_b[BN * BK];

    const int t    = threadIdx.x;
    const int lane = t & 63;
    const int wave = t >> 6;

    const int m0 = blockIdx.y * BM;
    const int n0 = blockIdx.x * BN;

    // staging: thread t covers tile elements [t*8 .. t*8+7]; row=t>>2, col=(t&3)*8
    const int srow = t >> 2;
    const int scol = (t & 3) * 8;
    const __hip_bfloat16* gA0 = A + (size_t)(m0 + srow) * KTOT + scol;
    const __hip_bfloat16* gA1 = gA0 + (size_t)64 * KTOT;
    const __hip_bfloat16* gB0 = W + (size_t)(n0 + srow) * KTOT + scol;
    const __hip_bfloat16* gB1 = gB0 + (size_t)64 * KTOT;

    char* lA = (char*)lds_a + wave * 1024;    // wave-uniform base; HW adds lane*16
    char* lB = (char*)lds_b + wave * 1024;

    const int wrow = (wave >> 1) * 64;
    const int wcol = (wave & 1) * 64;
    const int fr   = lane & 15;
    const int quad = lane >> 4;

    f32x4 acc[4][4];
    #pragma unroll
    for (int i = 0; i < 4; ++i)
        #pragma unroll
        for (int j = 0; j < 4; ++j)
            acc[i][j] = (f32x4){0.f, 0.f, 0.f, 0.f};

    const short* sa = (const short*)lds_a;
    const short* sb = (const short*)lds_b;

    for (int kt = 0; kt < KTOT / BK; ++kt) {
        if (kt) __syncthreads();
        const int kb = kt * BK;
        gload_lds16(gA0 + kb, lA);
        gload_lds16(gA1 + kb, lA + 4096);
        gload_lds16(gB0 + kb, lB);
        gload_lds16(gB1 + kb, lB + 4096);
        __syncthreads();                      // drains vmcnt before barrier

        short8 af[4], bf[4];
        #pragma unroll
        for (int i = 0; i < 4; ++i)
            af[i] = *(const short8*)(sa + (wrow + i * 16 + fr) * BK + quad * 8);
        #pragma unroll
        for (int j = 0; j < 4; ++j)
            bf[j] = *(const short8*)(sb + (wcol + j * 16 + fr) * BK + quad * 8);

        #pragma unroll
        for (int i = 0; i < 4; ++i)
            #pragma unroll
            for (int j = 0; j < 4; ++j)
                acc[i][j] = __builtin_amdgcn_mfma_f32_16x16x32_bf16(
                    af[i], bf[j], acc[i][j], 0, 0, 0);
    }

    // epilogue: C/D layout col=lane&15, row=quad*4+reg (m89-verified)
    float bv[4];
    #pragma unroll
    for (int j = 0; j < 4; ++j)
        bv[j] = bias[n0 + wcol + j * 16 + fr];

    #pragma unroll
    for (int i = 0; i < 4; ++i) {
        const int row = m0 + wrow + i * 16 + quad * 4;
        #pragma unroll
        for (int j = 0; j < 4; ++j) {
            float* p = C + (size_t)row * NTOT + (n0 + wcol + j * 16 + fr);
            #pragma unroll
            for (int r = 0; r < 4; ++r)
                p[(size_t)r * NTOT] = acc[i][j][r] + bv[j];
        }
    }
}

extern "C" void kernel_launch(void* const* d_in, const int* in_sizes, int n_in,
                              void* d_out, int out_size, void* d_ws, size_t ws_size,
                              hipStream_t stream) {
    const float* q  = (const float*)d_in[0];
    const float* Wq = (const float*)d_in[1];
    const float* bq = (const float*)d_in[2];
    float*       C  = (float*)d_out;

    char* ws = (char*)d_ws;
    unsigned short* wsA = (unsigned short*)(ws + WS_A_OFF);
    unsigned short* wsW = (unsigned short*)(ws + WS_W_OFF);

    // A: 8192 blocks, W: 1536 blocks (2048 elems/block each)
    cvt_aw<<<8192 + 1536, 256, 0, stream>>>(q, Wq, wsA, wsW);

    dim3 grid(NTOT / BN, MTOT / BM);   // (24, 128)
    qkv_gemm_bt<<<grid, 256, 0, stream>>>(
        (const __hip_bfloat16*)wsA, (const __hip_bfloat16*)wsW, bq, C);
}